// Round 10
// baseline (862.101 us; speedup 1.0000x reference)
//
#include <hip/hip_runtime.h>

#define B_ 8
#define C_ 256
#define H_ 64
#define W_ 64
#define HW_ 4096
#define HP_ 66          // padded rows
#define HWP_ 4224       // 66*64 padded plane
#define A_ 9
#define SITES 36864      // A_*HW_
#define NPOST 1000
#define XCLIPF 4.1351666f   // (float)4.135166556742356
#define IMGF 1024.0f

__device__ inline unsigned keyf(float v) {
  unsigned u = __float_as_uint(v);
  return (u & 0x80000000u) ? ~u : (u | 0x80000000u);  // ascending uint == ascending float
}

// DPP row shifts (16-lane rows). chunk boundaries (tid&15 == 0/15) coincide exactly with
// DPP row boundaries, so zero bound_ctrl reproduces the edge masking bit-exactly.
// HW-validated bit-exact in rounds 1-9 (absmax 0.0).
__device__ __forceinline__ float dpp_shr1(float v) {  // lane i <- lane i-1; row-pos 0 -> 0.0f
  return __int_as_float(__builtin_amdgcn_update_dpp(
      0, __float_as_int(v), 0x111 /*row_shr:1*/, 0xf, 0xf, true));
}
__device__ __forceinline__ float dpp_shl1(float v) {  // lane i <- lane i+1; row-pos 15 -> 0.0f
  return __int_as_float(__builtin_amdgcn_update_dpp(
      0, __float_as_int(v), 0x101 /*row_shl:1*/, 0xf, 0xf, true));
}

// ---------------- K0: prep = pad_x + pack_w(quad) + pack_wt(1x1 transpose), one launch ------
__global__ __launch_bounds__(256) void prep(
    const float* __restrict__ x, const float* __restrict__ w,
    const float* __restrict__ box_w, const float* __restrict__ obj_w,
    float* __restrict__ xp, float* __restrict__ wq, float* __restrict__ wt) {
  int blk = blockIdx.x;
  if (blk < 8448) {                              // pad: B_*C_*66*16 float4 = 8448 blocks
    int t = blk * 256 + threadIdx.x;
    int c4 = t & 15;
    int rr = (t >> 4) % HP_;
    int bc = t / (HP_ * 16);
    float4 v = make_float4(0.f, 0.f, 0.f, 0.f);
    if (rr >= 1 && rr <= 64)
      v = ((const float4*)x)[(size_t)bc * (HW_ / 4) + (size_t)(rr - 1) * 16 + c4];
    ((float4*)xp)[(size_t)bc * (HWP_ / 4) + (size_t)rr * 16 + c4] = v;
  } else if (blk < 8448 + 2304) {                // wq: 64*256*36 = 2304 blocks
    int idx = (blk - 8448) * 256 + threadIdx.x;
    int quad = idx / (256 * 36);
    int rem  = idx % (256 * 36);
    int ci = rem / 36;
    int k  = rem % 36;
    int q = k / 9, t = k % 9;
    wq[idx] = w[((size_t)(quad * 4 + q)) * (C_ * 9) + (size_t)ci * 9 + t];
  } else {                                       // wt: 256*45 = 45 blocks
    int idx = (blk - 8448 - 2304) * 256 + threadIdx.x;
    if (idx < C_ * 45) {
      int ci = idx / 45, jj = idx % 45;
      wt[idx] = (jj < 36) ? box_w[(size_t)jj * C_ + ci]
                          : obj_w[(size_t)(jj - 36) * C_ + ci];
    }
  }
}

// ---------------- K1: 3x3 conv + bias + relu, bit-exact f32, 4 co x 4 px per thread ----------
// Round-4 VALIDATED config, verbatim (561-568us, VGPR 108): padded input, packed weights,
// unroll 2, DPP halo. unroll 4 regressed (r5); manual pipeline regressed (r1); 2co split
// regressed (r2). Pinned optimum for the strip decomposition.
__global__ __launch_bounds__(256, 2) void conv3_4co(
    const float* __restrict__ xp, const float* __restrict__ wq,
    const float* __restrict__ bias, float* __restrict__ feats) {
#pragma clang fp contract(off)
  int b       = blockIdx.x & 7;        // XCD-affine (perf-only)
  int j       = blockIdx.x >> 3;       // 0..255
  int quad    = j & 63;                // co quad
  int quarter = j >> 6;                // 0..3 (16-row band)
  int co0 = quad << 2;
  int row16 = threadIdx.x >> 4;        // 0..15
  int chunk = threadIdx.x & 15;        // 0..15
  int gr = (quarter << 4) + row16;     // output row 0..63
  int c0 = chunk << 2;                 // col base (16B aligned)

  const float* px0 = xp + (size_t)b * C_ * HWP_ + (size_t)gr * W_ + c0;
  const float* wqb = wq + (size_t)quad * (C_ * 36);

  float acc[4][4][9];                  // [co][px][tap]
#pragma unroll
  for (int q = 0; q < 4; ++q)
#pragma unroll
    for (int p = 0; p < 4; ++p)
#pragma unroll
      for (int t = 0; t < 9; ++t) acc[q][p][t] = 0.f;

#pragma unroll 2
  for (int ci = 0; ci < C_; ++ci) {
    const float* pr = px0 + (size_t)ci * HWP_;
    float4 tA = ((const float4*)(pr      ))[0];   // row gr-1 (padded row gr)
    float4 mA = ((const float4*)(pr +  64))[0];   // row gr
    float4 bA = ((const float4*)(pr + 128))[0];   // row gr+1

    float T[6], M[6], Bo[6];           // cols c0-1 .. c0+4
    T[1]=tA.x;  T[2]=tA.y;  T[3]=tA.z;  T[4]=tA.w;
    M[1]=mA.x;  M[2]=mA.y;  M[3]=mA.z;  M[4]=mA.w;
    Bo[1]=bA.x; Bo[2]=bA.y; Bo[3]=bA.z; Bo[4]=bA.w;

    T[0]  = dpp_shr1(T[4]);   T[5]  = dpp_shl1(T[1]);
    M[0]  = dpp_shr1(M[4]);   M[5]  = dpp_shl1(M[1]);
    Bo[0] = dpp_shr1(Bo[4]);  Bo[5] = dpp_shl1(Bo[1]);

    const float* wrow = wqb + ci * 36;  // wave-uniform, contiguous 144B
    float w9[4][9];
#pragma unroll
    for (int q = 0; q < 4; ++q)
#pragma unroll
      for (int t = 0; t < 9; ++t) w9[q][t] = wrow[q * 9 + t];

#pragma unroll
    for (int q = 0; q < 4; ++q)
#pragma unroll
      for (int p = 0; p < 4; ++p) {
        acc[q][p][0] = fmaf(w9[q][0], T[p],     acc[q][p][0]);
        acc[q][p][1] = fmaf(w9[q][1], T[p+1],   acc[q][p][1]);
        acc[q][p][2] = fmaf(w9[q][2], T[p+2],   acc[q][p][2]);
        acc[q][p][3] = fmaf(w9[q][3], M[p],     acc[q][p][3]);
        acc[q][p][4] = fmaf(w9[q][4], M[p+1],   acc[q][p][4]);
        acc[q][p][5] = fmaf(w9[q][5], M[p+2],   acc[q][p][5]);
        acc[q][p][6] = fmaf(w9[q][6], Bo[p],    acc[q][p][6]);
        acc[q][p][7] = fmaf(w9[q][7], Bo[p+1],  acc[q][p][7]);
        acc[q][p][8] = fmaf(w9[q][8], Bo[p+2],  acc[q][p][8]);
      }
  }

#pragma unroll
  for (int q = 0; q < 4; ++q) {
    float bv = bias[co0 + q];
    float ov[4];
#pragma unroll
    for (int p = 0; p < 4; ++p) {
      float a = 0.f;
#pragma unroll
      for (int t = 0; t < 9; ++t) a = a + acc[q][p][t];  // tap-ordered, left-assoc
      a = a + bv;
      ov[p] = a > 0.f ? a : 0.f;
    }
    float4* fo = (float4*)(feats + ((size_t)b * C_ + co0 + q) * HW_ + (size_t)gr * W_ + c0);
    fo[0] = make_float4(ov[0], ov[1], ov[2], ov[3]);
  }
}

// ---------------- K2: 1x1 convs, ALL 45 chains per thread, feats read ONCE ----------------
// VALIDATED structure (r6/r9 benches): 1x feats read is the optimum (3x and 5x splits both
// regressed). This round: unroll 4 -> 8 — at 2 waves/CU the 400cy load latency needs ~8
// loads in flight to hide under ~90cy of FMA per iteration; +4 VGPR, no occupancy change.
// Per-output fmaf chain over ci ascending is verbatim -> bit-exact.
__global__ __launch_bounds__(64) void conv1_all45(
    const float* __restrict__ feats, const float* __restrict__ wt,
    const float* __restrict__ box_b, const float* __restrict__ obj_b,
    float* __restrict__ tbox, float* __restrict__ scores) {
#pragma clang fp contract(off)
  int gidx = blockIdx.x * 64 + threadIdx.x;   // [0, B_*HW_)
  int b  = gidx >> 12;
  int hw = gidx & 4095;
  const float* f = feats + (size_t)b * C_ * HW_ + hw;
  float acc[45];
#pragma unroll
  for (int jj = 0; jj < 45; ++jj) acc[jj] = 0.f;
#pragma unroll 8
  for (int ci = 0; ci < C_; ++ci) {
    float fv = f[(size_t)ci * HW_];
    const float* wr = wt + ci * 45;            // wave-uniform, contiguous 180B
#pragma unroll
    for (int jj = 0; jj < 45; ++jj)
      acc[jj] = fmaf(wr[jj], fv, acc[jj]);
  }
#pragma unroll
  for (int c = 0; c < 36; ++c) {
    int k = c / 9, a = c - k * 9;
    tbox[(size_t)b * 4 * SITES + (size_t)k * SITES + (size_t)a * HW_ + hw] = acc[c] + box_b[c];
  }
#pragma unroll
  for (int a = 0; a < 9; ++a)
    scores[(size_t)b * SITES + (size_t)a * HW_ + hw] = acc[36 + a] + obj_b[a];
}

// ---------------- K3: fused select+sort+decode, one block per batch ----------------
// r9-validated structure (register key cache, plain HW atomics — both software-aggregation
// variants regressed, r7/r8). This round: per-WAVE private histograms (16 copies, 16KB LDS,
// still HW atomics). Clustered pass-1 keys hit ~2-6 bins; same-address LDS atomics
// serialize, so 16 private copies cut the serialization depth 16x. Final counts = sum of
// per-wave counts -> identical selection decisions -> bit-exact.
__global__ __launch_bounds__(1024) void select_sort_decode(
    const float* __restrict__ scores, const float* __restrict__ tbox,
    float* __restrict__ s2, float* __restrict__ b2) {
#pragma clang fp contract(off)
  int b = blockIdx.x;
  const float* s = scores + (size_t)b * SITES;
  __shared__ unsigned histp[16][256];     // per-wave private histograms (16KB)
  __shared__ unsigned hist[256];
  __shared__ unsigned sh_prefix, sh_mask, sh_cless;
  __shared__ int sh_target;
  __shared__ int sh_cnt, sh_eq;
  __shared__ int sh_sel[1024];
  __shared__ int sh_eqList[4096];
  __shared__ float ss[NPOST];
  __shared__ int st[NPOST];
  int wid = threadIdx.x >> 6;             // wave id 0..15
  if (threadIdx.x == 0) {
    sh_prefix = 0; sh_mask = 0; sh_target = NPOST - 1; sh_cless = 0;
    sh_cnt = 0; sh_eq = 0;
  }
  // ---- key cache: 36 keys/thread, one global sweep total ----
  unsigned kreg[36];
#pragma unroll
  for (int t = 0; t < 36; ++t)
    kreg[t] = keyf(s[threadIdx.x + t * 1024]);
  // ---- phase 1: radix-select the 1000th-smallest key ----
  for (int shift = 24; shift >= 0; shift -= 8) {
    for (int z = threadIdx.x; z < 16 * 256; z += 1024) ((unsigned*)histp)[z] = 0;
    __syncthreads();
    unsigned prefix = sh_prefix, mask = sh_mask;
#pragma unroll
    for (int t = 0; t < 36; ++t) {
      unsigned k = kreg[t];
      if ((k & mask) == prefix) atomicAdd(&histp[wid][(k >> shift) & 255u], 1u);
    }
    __syncthreads();
    if (threadIdx.x < 256) {
      unsigned sum = 0;
#pragma unroll
      for (int wv = 0; wv < 16; ++wv) sum += histp[wv][threadIdx.x];
      hist[threadIdx.x] = sum;
    }
    __syncthreads();
    if (threadIdx.x == 0) {
      unsigned cum = 0; int tg = sh_target; int v = 0;
      for (; v < 256; ++v) {
        unsigned h = hist[v];
        if (cum + h > (unsigned)tg) break;
        cum += h;
      }
      sh_prefix |= ((unsigned)v) << shift;
      sh_mask   |= 0xFFu << shift;
      sh_target  = tg - (int)cum;
      sh_cless  += cum;
    }
    __syncthreads();
  }
  unsigned K = sh_prefix;
  int need = NPOST - (int)sh_cless;
  // ---- phase 2: compact k<K sites; collect k==K sites (register keys) ----
#pragma unroll
  for (int t = 0; t < 36; ++t) {
    unsigned k = kreg[t];
    int i = threadIdx.x + t * 1024;
    if (k < K) {
      int pos = atomicAdd(&sh_cnt, 1);
      sh_sel[pos] = i;                 // arbitrary order: phase 4 re-ranks
    } else if (k == K) {
      int e = atomicAdd(&sh_eq, 1);
      if (e < 4096) sh_eqList[e] = i;
    }
  }
  __syncthreads();
  // ---- phase 3: take the need smallest-index equal-key sites ----
  {
    int E = sh_eq; if (E > 4096) E = 4096;
    int base = sh_cnt;
    for (int t = threadIdx.x; t < E; t += 1024) {
      int site = sh_eqList[t];
      int rank = 0;
      for (int q = 0; q < E; ++q) rank += (sh_eqList[q] < site);
      if (rank < need) sh_sel[base + rank] = site;
    }
  }
  __syncthreads();
  // ---- phase 4: descending order + fused decode (verbatim math) ----
  for (int t = threadIdx.x; t < NPOST; t += 1024) {
    int site = sh_sel[t];
    st[t] = site;
    ss[t] = s[site];
  }
  __syncthreads();
  if (threadIdx.x < NPOST) {
    int r = threadIdx.x;
    float sr = ss[r]; int sir = st[r];
    int d = 0;
    for (int q = 0; q < NPOST; ++q) {
      float sq = ss[q];
      d += (int)((sq > sr) || (sq == sr && st[q] < sir));
    }
    s2[(size_t)b * NPOST + d] = sr;
    int site = sir;
    int a = site / HW_;
    int hw = site - a * HW_;
    int h = hw / W_, wc = hw - h * W_;
    int sidx = a / 3, ridx = a - sidx * 3;
    float scale = (sidx == 0) ? 128.f : ((sidx == 1) ? 256.f : 512.f);
    float ratio = (ridx == 0) ? 0.5f : ((ridx == 1) ? 1.0f : 2.0f);
    float sq = sqrtf(ratio);
    float wsa = scale / sq;
    float hsa = scale * sq;
    float cx = ((float)wc + 0.5f) * 16.f;
    float cy = ((float)h + 0.5f) * 16.f;
    float ax1 = cx - wsa * 0.5f;
    float ay1 = cy - hsa * 0.5f;
    float ax2 = cx + wsa * 0.5f;
    float ay2 = cy + hsa * 0.5f;
    float aw = ax2 - ax1, ah = ay2 - ay1;
    float m1 = 0.5f * aw, m2 = 0.5f * ah;
    float acx = ax1 + m1, acy = ay1 + m2;
    const float* tb = tbox + (size_t)b * 4 * SITES + site;
    float t0 = tb[0];
    float t1 = tb[SITES];
    float t2 = tb[2 * (size_t)SITES];
    float t3 = tb[3 * (size_t)SITES];
    if (t2 < -XCLIPF) t2 = -XCLIPF;
    if (t2 > XCLIPF) t2 = XCLIPF;
    if (t3 < -XCLIPF) t3 = -XCLIPF;
    if (t3 > XCLIPF) t3 = XCLIPF;
    float pm0 = t0 * aw;  float pcx = pm0 + acx;
    float pm1 = t1 * ah;  float pcy = pm1 + acy;
    float pw = expf(t2) * aw;
    float ph = expf(t3) * ah;
    float hw0 = 0.5f * pw, hh0 = 0.5f * ph;
    float x1 = pcx - hw0, y1 = pcy - hh0;
    float x2 = pcx + hw0, y2 = pcy + hh0;
    x1 = x1 < 0.f ? 0.f : (x1 > IMGF ? IMGF : x1);
    y1 = y1 < 0.f ? 0.f : (y1 > IMGF ? IMGF : y1);
    x2 = x2 < 0.f ? 0.f : (x2 > IMGF ? IMGF : x2);
    y2 = y2 < 0.f ? 0.f : (y2 > IMGF ? IMGF : y2);
    float* o = b2 + ((size_t)b * NPOST + d) * 4;
    o[0] = x1; o[1] = y1; o[2] = x2; o[3] = y2;
  }
}

// ---------------- K6a: suppression bitmask, f32 exact op order; conflict-fixed mapping ----------
__global__ __launch_bounds__(256) void mask_kernel(
    const float* __restrict__ b2, unsigned long long* __restrict__ sup) {
#pragma clang fp contract(off)
  int b = blockIdx.x / 63;
  int i0 = (blockIdx.x % 63) * 16;
  __shared__ float bs[NPOST * 4];
  __shared__ float area[NPOST];
  for (int t = threadIdx.x; t < NPOST * 4; t += 256) bs[t] = b2[(size_t)b * NPOST * 4 + t];
  __syncthreads();
  for (int t = threadIdx.x; t < NPOST; t += 256)
    area[t] = (bs[t * 4 + 2] - bs[t * 4]) * (bs[t * 4 + 3] - bs[t * 4 + 1]);
  __syncthreads();
  int i = i0 + (threadIdx.x & 15);
  int wd = threadIdx.x >> 4;
  if (i >= NPOST) return;
  float ax1 = bs[i * 4], ay1 = bs[i * 4 + 1], ax2 = bs[i * 4 + 2], ay2 = bs[i * 4 + 3];
  float aa = area[i];
  unsigned long long m = 0;
  for (int bit = 0; bit < 64; ++bit) {
    int j = wd * 64 + bit;
    if (j > i && j < NPOST) {
      float lx = fmaxf(ax1, bs[j * 4]);
      float ly = fmaxf(ay1, bs[j * 4 + 1]);
      float rx = fminf(ax2, bs[j * 4 + 2]);
      float ry = fminf(ay2, bs[j * 4 + 3]);
      float iw = rx - lx; if (iw < 0.f) iw = 0.f;
      float ih = ry - ly; if (ih < 0.f) ih = 0.f;
      float inter = iw * ih;
      float denom = (aa + area[j]) - inter;
      float iou = inter / denom;
      if (iou > 0.7f) m |= 1ull << bit;
    }
  }
  sup[((size_t)b * NPOST + i) * 16 + wd] = m;
}

// ---------------- K6b: wave-synchronous NMS scan, 8-deep prefetch + compaction ----------------
__global__ __launch_bounds__(64) void nms_out(
    const unsigned long long* __restrict__ sup, const float* __restrict__ b2,
    const float* __restrict__ s2, float* __restrict__ out) {
  int b = blockIdx.x;
  int lane = threadIdx.x;
  unsigned long long kw = 0;
  if (lane < 16) kw = (lane < 15) ? ~0ull : ((1ull << 40) - 1);  // bits 960..999 valid
  const unsigned long long* ms = sup + (size_t)b * NPOST * 16;
  unsigned long long mb[8];
#pragma unroll
  for (int k = 0; k < 8; ++k)
    mb[k] = (lane < 16) ? ms[(size_t)k * 16 + lane] : 0ull;
  for (int i0 = 0; i0 < NPOST; i0 += 8) {          // 1000 = 8*125
    unsigned long long nb[8];
#pragma unroll
    for (int k = 0; k < 8; ++k) {
      int nx = i0 + 8 + k;
      nb[k] = (nx < NPOST && lane < 16) ? ms[(size_t)nx * 16 + lane] : 0ull;
    }
#pragma unroll
    for (int k = 0; k < 8; ++k) {
      int i = i0 + k;
      unsigned long long w = __shfl(kw, i >> 6, 64);  // broadcast word holding bit i
      if ((w >> (i & 63)) & 1ull) {                   // wave-uniform branch
        if (lane < 16) kw &= ~mb[k];                  // bit i never set in row i (j>i only)
      }
    }
#pragma unroll
    for (int k = 0; k < 8; ++k) mb[k] = nb[k];
  }
  __shared__ unsigned long long keeps[16];
  if (lane < 16) keeps[lane] = kw;
  __syncthreads();
  int total = 0;
#pragma unroll
  for (int k = 0; k < 16; ++k) total += __popcll(keeps[k]);
  for (int i = lane; i < NPOST; i += 64) {
    int w = i >> 6;
    int before = 0;
    for (int k = 0; k < w; ++k) before += __popcll(keeps[k]);
    before += __popcll(keeps[w] & ((1ull << (i & 63)) - 1));
    bool kept = (keeps[w] >> (i & 63)) & 1ull;
    if (kept) {
      size_t ob = (size_t)b * (NPOST * 5) + (size_t)before * 5;
      const float* src = b2 + ((size_t)b * NPOST + i) * 4;
      out[ob + 0] = src[0];
      out[ob + 1] = src[1];
      out[ob + 2] = src[2];
      out[ob + 3] = src[3];
      out[ob + 4] = s2[(size_t)b * NPOST + i];
    }
    if (i >= total) {
      size_t ob = (size_t)b * (NPOST * 5) + (size_t)i * 5;
      for (int c = 0; c < 5; ++c) out[ob + c] = 0.f;
    }
  }
}

extern "C" void kernel_launch(void* const* d_in, const int* in_sizes, int n_in,
                              void* d_out, int out_size, void* d_ws, size_t ws_size,
                              hipStream_t stream) {
  const float *x = nullptr, *conv_w = nullptr, *conv_b = nullptr,
              *box_w = nullptr, *box_b = nullptr, *obj_w = nullptr, *obj_b = nullptr;
  for (int i = 0; i < n_in; ++i) {
    switch (in_sizes[i]) {
      case 8388608: x = (const float*)d_in[i]; break;
      case 589824:  conv_w = (const float*)d_in[i]; break;
      case 256:     conv_b = (const float*)d_in[i]; break;
      case 9216:    box_w = (const float*)d_in[i]; break;
      case 36:      box_b = (const float*)d_in[i]; break;
      case 2304:    obj_w = (const float*)d_in[i]; break;
      case 9:       obj_b = (const float*)d_in[i]; break;
    }
  }
  float* out = (float*)d_out;

  char* p = (char*)d_ws;
  auto alloc = [&](size_t n) { char* q = p; p += (n + 255) & ~255ull; return (void*)q; };
  float* feats  = (float*)alloc((size_t)B_ * C_ * HW_ * 4);       // 33.55 MB
  float* tbox   = (float*)alloc((size_t)B_ * 4 * SITES * 4);      // 4.72 MB
  float* scores = (float*)alloc((size_t)B_ * SITES * 4);          // 1.18 MB
  float* xpad   = (float*)alloc((size_t)B_ * C_ * HWP_ * 4);      // 34.60 MB
  float* wq     = (float*)alloc((size_t)64 * C_ * 36 * 4);        // 2.36 MB packed 3x3 weights
  float* wt     = (float*)alloc((size_t)C_ * 45 * 4);             // 46 KB packed 1x1 weights
  float* s2     = (float*)alloc((size_t)B_ * NPOST * 4);
  float* b2     = (float*)alloc((size_t)B_ * NPOST * 4 * 4);
  unsigned long long* sup = (unsigned long long*)alloc((size_t)B_ * NPOST * 16 * 8); // 1.02 MB

  hipLaunchKernelGGL(prep, dim3(8448 + 2304 + 45), dim3(256), 0, stream,
                     x, conv_w, box_w, obj_w, xpad, wq, wt);
  hipLaunchKernelGGL(conv3_4co, dim3(B_ * 64 * 4), dim3(256), 0, stream,
                     xpad, wq, conv_b, feats);
  hipLaunchKernelGGL(conv1_all45, dim3(B_ * HW_ / 64), dim3(64), 0, stream,
                     feats, wt, box_b, obj_b, tbox, scores);
  hipLaunchKernelGGL(select_sort_decode, dim3(B_), dim3(1024), 0, stream,
                     scores, tbox, s2, b2);
  hipLaunchKernelGGL(mask_kernel, dim3(B_ * 63), dim3(256), 0, stream, b2, sup);
  hipLaunchKernelGGL(nms_out, dim3(B_), dim3(64), 0, stream, sup, b2, s2, out);
}

// Round 11
// 846.830 us; speedup vs baseline: 1.0180x; 1.0180x over previous
//
#include <hip/hip_runtime.h>

#define B_ 8
#define C_ 256
#define H_ 64
#define W_ 64
#define HW_ 4096
#define HP_ 66          // padded rows
#define HWP_ 4224       // 66*64 padded plane
#define A_ 9
#define SITES 36864      // A_*HW_
#define NPOST 1000
#define XCLIPF 4.1351666f   // (float)4.135166556742356
#define IMGF 1024.0f

__device__ inline unsigned keyf(float v) {
  unsigned u = __float_as_uint(v);
  return (u & 0x80000000u) ? ~u : (u | 0x80000000u);  // ascending uint == ascending float
}

// DPP row shifts (16-lane rows). chunk boundaries (tid&15 == 0/15) coincide exactly with
// DPP row boundaries, so zero bound_ctrl reproduces the edge masking bit-exactly.
// HW-validated bit-exact in rounds 1-10 (absmax 0.0).
__device__ __forceinline__ float dpp_shr1(float v) {  // lane i <- lane i-1; row-pos 0 -> 0.0f
  return __int_as_float(__builtin_amdgcn_update_dpp(
      0, __float_as_int(v), 0x111 /*row_shr:1*/, 0xf, 0xf, true));
}
__device__ __forceinline__ float dpp_shl1(float v) {  // lane i <- lane i+1; row-pos 15 -> 0.0f
  return __int_as_float(__builtin_amdgcn_update_dpp(
      0, __float_as_int(v), 0x101 /*row_shl:1*/, 0xf, 0xf, true));
}

// ---------------- K0: prep = pad_x + pack_w(quad) + pack_wt(1x1 transpose), one launch ------
__global__ __launch_bounds__(256) void prep(
    const float* __restrict__ x, const float* __restrict__ w,
    const float* __restrict__ box_w, const float* __restrict__ obj_w,
    float* __restrict__ xp, float* __restrict__ wq, float* __restrict__ wt) {
  int blk = blockIdx.x;
  if (blk < 8448) {                              // pad: B_*C_*66*16 float4 = 8448 blocks
    int t = blk * 256 + threadIdx.x;
    int c4 = t & 15;
    int rr = (t >> 4) % HP_;
    int bc = t / (HP_ * 16);
    float4 v = make_float4(0.f, 0.f, 0.f, 0.f);
    if (rr >= 1 && rr <= 64)
      v = ((const float4*)x)[(size_t)bc * (HW_ / 4) + (size_t)(rr - 1) * 16 + c4];
    ((float4*)xp)[(size_t)bc * (HWP_ / 4) + (size_t)rr * 16 + c4] = v;
  } else if (blk < 8448 + 2304) {                // wq: 64*256*36 = 2304 blocks
    int idx = (blk - 8448) * 256 + threadIdx.x;
    int quad = idx / (256 * 36);
    int rem  = idx % (256 * 36);
    int ci = rem / 36;
    int k  = rem % 36;
    int q = k / 9, t = k % 9;
    wq[idx] = w[((size_t)(quad * 4 + q)) * (C_ * 9) + (size_t)ci * 9 + t];
  } else {                                       // wt: 256*45 = 45 blocks
    int idx = (blk - 8448 - 2304) * 256 + threadIdx.x;
    if (idx < C_ * 45) {
      int ci = idx / 45, jj = idx % 45;
      wt[idx] = (jj < 36) ? box_w[(size_t)jj * C_ + ci]
                          : obj_w[(size_t)(jj - 36) * C_ + ci];
    }
  }
}

// ---------------- K1: 3x3 conv + bias + relu, bit-exact f32, 4 co x 4 px per thread ----------
// Round-4 VALIDATED config, verbatim (561-568us, VGPR 108): padded input, packed weights,
// unroll 2, DPP halo. All deviations regressed: manual pipeline (r1), 2co TLP split (r2),
// unroll 4 (r5). Pinned optimum for the strip decomposition.
__global__ __launch_bounds__(256, 2) void conv3_4co(
    const float* __restrict__ xp, const float* __restrict__ wq,
    const float* __restrict__ bias, float* __restrict__ feats) {
#pragma clang fp contract(off)
  int b       = blockIdx.x & 7;        // XCD-affine (perf-only)
  int j       = blockIdx.x >> 3;       // 0..255
  int quad    = j & 63;                // co quad
  int quarter = j >> 6;                // 0..3 (16-row band)
  int co0 = quad << 2;
  int row16 = threadIdx.x >> 4;        // 0..15
  int chunk = threadIdx.x & 15;        // 0..15
  int gr = (quarter << 4) + row16;     // output row 0..63
  int c0 = chunk << 2;                 // col base (16B aligned)

  const float* px0 = xp + (size_t)b * C_ * HWP_ + (size_t)gr * W_ + c0;
  const float* wqb = wq + (size_t)quad * (C_ * 36);

  float acc[4][4][9];                  // [co][px][tap]
#pragma unroll
  for (int q = 0; q < 4; ++q)
#pragma unroll
    for (int p = 0; p < 4; ++p)
#pragma unroll
      for (int t = 0; t < 9; ++t) acc[q][p][t] = 0.f;

#pragma unroll 2
  for (int ci = 0; ci < C_; ++ci) {
    const float* pr = px0 + (size_t)ci * HWP_;
    float4 tA = ((const float4*)(pr      ))[0];   // row gr-1 (padded row gr)
    float4 mA = ((const float4*)(pr +  64))[0];   // row gr
    float4 bA = ((const float4*)(pr + 128))[0];   // row gr+1

    float T[6], M[6], Bo[6];           // cols c0-1 .. c0+4
    T[1]=tA.x;  T[2]=tA.y;  T[3]=tA.z;  T[4]=tA.w;
    M[1]=mA.x;  M[2]=mA.y;  M[3]=mA.z;  M[4]=mA.w;
    Bo[1]=bA.x; Bo[2]=bA.y; Bo[3]=bA.z; Bo[4]=bA.w;

    T[0]  = dpp_shr1(T[4]);   T[5]  = dpp_shl1(T[1]);
    M[0]  = dpp_shr1(M[4]);   M[5]  = dpp_shl1(M[1]);
    Bo[0] = dpp_shr1(Bo[4]);  Bo[5] = dpp_shl1(Bo[1]);

    const float* wrow = wqb + ci * 36;  // wave-uniform, contiguous 144B
    float w9[4][9];
#pragma unroll
    for (int q = 0; q < 4; ++q)
#pragma unroll
      for (int t = 0; t < 9; ++t) w9[q][t] = wrow[q * 9 + t];

#pragma unroll
    for (int q = 0; q < 4; ++q)
#pragma unroll
      for (int p = 0; p < 4; ++p) {
        acc[q][p][0] = fmaf(w9[q][0], T[p],     acc[q][p][0]);
        acc[q][p][1] = fmaf(w9[q][1], T[p+1],   acc[q][p][1]);
        acc[q][p][2] = fmaf(w9[q][2], T[p+2],   acc[q][p][2]);
        acc[q][p][3] = fmaf(w9[q][3], M[p],     acc[q][p][3]);
        acc[q][p][4] = fmaf(w9[q][4], M[p+1],   acc[q][p][4]);
        acc[q][p][5] = fmaf(w9[q][5], M[p+2],   acc[q][p][5]);
        acc[q][p][6] = fmaf(w9[q][6], Bo[p],    acc[q][p][6]);
        acc[q][p][7] = fmaf(w9[q][7], Bo[p+1],  acc[q][p][7]);
        acc[q][p][8] = fmaf(w9[q][8], Bo[p+2],  acc[q][p][8]);
      }
  }

#pragma unroll
  for (int q = 0; q < 4; ++q) {
    float bv = bias[co0 + q];
    float ov[4];
#pragma unroll
    for (int p = 0; p < 4; ++p) {
      float a = 0.f;
#pragma unroll
      for (int t = 0; t < 9; ++t) a = a + acc[q][p][t];  // tap-ordered, left-assoc
      a = a + bv;
      ov[p] = a > 0.f ? a : 0.f;
    }
    float4* fo = (float4*)(feats + ((size_t)b * C_ + co0 + q) * HW_ + (size_t)gr * W_ + c0);
    fo[0] = make_float4(ov[0], ov[1], ov[2], ov[3]);
  }
}

// ---------------- K2: 1x1 convs, ALL 45 chains per thread, feats read ONCE ----------------
// VALIDATED (r9 bench, 850.6us config): 1x feats read (3x/5x splits regressed), unroll 4
// (unroll 8 regressed in r10). Per-output fmaf chain over ci ascending -> bit-exact.
__global__ __launch_bounds__(64) void conv1_all45(
    const float* __restrict__ feats, const float* __restrict__ wt,
    const float* __restrict__ box_b, const float* __restrict__ obj_b,
    float* __restrict__ tbox, float* __restrict__ scores) {
#pragma clang fp contract(off)
  int gidx = blockIdx.x * 64 + threadIdx.x;   // [0, B_*HW_)
  int b  = gidx >> 12;
  int hw = gidx & 4095;
  const float* f = feats + (size_t)b * C_ * HW_ + hw;
  float acc[45];
#pragma unroll
  for (int jj = 0; jj < 45; ++jj) acc[jj] = 0.f;
#pragma unroll 4
  for (int ci = 0; ci < C_; ++ci) {
    float fv = f[(size_t)ci * HW_];
    const float* wr = wt + ci * 45;            // wave-uniform, contiguous 180B
#pragma unroll
    for (int jj = 0; jj < 45; ++jj)
      acc[jj] = fmaf(wr[jj], fv, acc[jj]);
  }
#pragma unroll
  for (int c = 0; c < 36; ++c) {
    int k = c / 9, a = c - k * 9;
    tbox[(size_t)b * 4 * SITES + (size_t)k * SITES + (size_t)a * HW_ + hw] = acc[c] + box_b[c];
  }
#pragma unroll
  for (int a = 0; a < 9; ++a)
    scores[(size_t)b * SITES + (size_t)a * HW_ + hw] = acc[36 + a] + obj_b[a];
}

// ---------------- K3: fused select+sort+decode, one block per batch ----------------
// r9 VALIDATED form (850.6us config): register key cache (36 keys/thread, one global
// sweep), plain per-lane HW LDS atomics (all software-aggregation and privatized-histogram
// variants regressed — r7/r8/r10). Arbitrary-order compaction re-ranked in phase 4 ->
// bit-exact.
__global__ __launch_bounds__(1024) void select_sort_decode(
    const float* __restrict__ scores, const float* __restrict__ tbox,
    float* __restrict__ s2, float* __restrict__ b2) {
#pragma clang fp contract(off)
  int b = blockIdx.x;
  const float* s = scores + (size_t)b * SITES;
  __shared__ unsigned hist[256];
  __shared__ unsigned sh_prefix, sh_mask, sh_cless;
  __shared__ int sh_target;
  __shared__ int sh_cnt, sh_eq;
  __shared__ int sh_sel[1024];
  __shared__ int sh_eqList[4096];
  __shared__ float ss[NPOST];
  __shared__ int st[NPOST];
  if (threadIdx.x == 0) {
    sh_prefix = 0; sh_mask = 0; sh_target = NPOST - 1; sh_cless = 0;
    sh_cnt = 0; sh_eq = 0;
  }
  // ---- key cache: 36 keys/thread, one global sweep total ----
  unsigned kreg[36];
#pragma unroll
  for (int t = 0; t < 36; ++t)
    kreg[t] = keyf(s[threadIdx.x + t * 1024]);
  // ---- phase 1: radix-select the 1000th-smallest key ----
  for (int shift = 24; shift >= 0; shift -= 8) {
    if (threadIdx.x < 256) hist[threadIdx.x] = 0;
    __syncthreads();
    unsigned prefix = sh_prefix, mask = sh_mask;
#pragma unroll
    for (int t = 0; t < 36; ++t) {
      unsigned k = kreg[t];
      if ((k & mask) == prefix) atomicAdd(&hist[(k >> shift) & 255u], 1u);
    }
    __syncthreads();
    if (threadIdx.x == 0) {
      unsigned cum = 0; int tg = sh_target; int v = 0;
      for (; v < 256; ++v) {
        unsigned h = hist[v];
        if (cum + h > (unsigned)tg) break;
        cum += h;
      }
      sh_prefix |= ((unsigned)v) << shift;
      sh_mask   |= 0xFFu << shift;
      sh_target  = tg - (int)cum;
      sh_cless  += cum;
    }
    __syncthreads();
  }
  unsigned K = sh_prefix;
  int need = NPOST - (int)sh_cless;
  // ---- phase 2: compact k<K sites; collect k==K sites (register keys) ----
#pragma unroll
  for (int t = 0; t < 36; ++t) {
    unsigned k = kreg[t];
    int i = threadIdx.x + t * 1024;
    if (k < K) {
      int pos = atomicAdd(&sh_cnt, 1);
      sh_sel[pos] = i;                 // arbitrary order: phase 4 re-ranks
    } else if (k == K) {
      int e = atomicAdd(&sh_eq, 1);
      if (e < 4096) sh_eqList[e] = i;
    }
  }
  __syncthreads();
  // ---- phase 3: take the need smallest-index equal-key sites ----
  {
    int E = sh_eq; if (E > 4096) E = 4096;
    int base = sh_cnt;
    for (int t = threadIdx.x; t < E; t += 1024) {
      int site = sh_eqList[t];
      int rank = 0;
      for (int q = 0; q < E; ++q) rank += (sh_eqList[q] < site);
      if (rank < need) sh_sel[base + rank] = site;
    }
  }
  __syncthreads();
  // ---- phase 4: descending order + fused decode (verbatim math) ----
  for (int t = threadIdx.x; t < NPOST; t += 1024) {
    int site = sh_sel[t];
    st[t] = site;
    ss[t] = s[site];
  }
  __syncthreads();
  if (threadIdx.x < NPOST) {
    int r = threadIdx.x;
    float sr = ss[r]; int sir = st[r];
    int d = 0;
    for (int q = 0; q < NPOST; ++q) {
      float sq = ss[q];
      d += (int)((sq > sr) || (sq == sr && st[q] < sir));
    }
    s2[(size_t)b * NPOST + d] = sr;
    int site = sir;
    int a = site / HW_;
    int hw = site - a * HW_;
    int h = hw / W_, wc = hw - h * W_;
    int sidx = a / 3, ridx = a - sidx * 3;
    float scale = (sidx == 0) ? 128.f : ((sidx == 1) ? 256.f : 512.f);
    float ratio = (ridx == 0) ? 0.5f : ((ridx == 1) ? 1.0f : 2.0f);
    float sq = sqrtf(ratio);
    float wsa = scale / sq;
    float hsa = scale * sq;
    float cx = ((float)wc + 0.5f) * 16.f;
    float cy = ((float)h + 0.5f) * 16.f;
    float ax1 = cx - wsa * 0.5f;
    float ay1 = cy - hsa * 0.5f;
    float ax2 = cx + wsa * 0.5f;
    float ay2 = cy + hsa * 0.5f;
    float aw = ax2 - ax1, ah = ay2 - ay1;
    float m1 = 0.5f * aw, m2 = 0.5f * ah;
    float acx = ax1 + m1, acy = ay1 + m2;
    const float* tb = tbox + (size_t)b * 4 * SITES + site;
    float t0 = tb[0];
    float t1 = tb[SITES];
    float t2 = tb[2 * (size_t)SITES];
    float t3 = tb[3 * (size_t)SITES];
    if (t2 < -XCLIPF) t2 = -XCLIPF;
    if (t2 > XCLIPF) t2 = XCLIPF;
    if (t3 < -XCLIPF) t3 = -XCLIPF;
    if (t3 > XCLIPF) t3 = XCLIPF;
    float pm0 = t0 * aw;  float pcx = pm0 + acx;
    float pm1 = t1 * ah;  float pcy = pm1 + acy;
    float pw = expf(t2) * aw;
    float ph = expf(t3) * ah;
    float hw0 = 0.5f * pw, hh0 = 0.5f * ph;
    float x1 = pcx - hw0, y1 = pcy - hh0;
    float x2 = pcx + hw0, y2 = pcy + hh0;
    x1 = x1 < 0.f ? 0.f : (x1 > IMGF ? IMGF : x1);
    y1 = y1 < 0.f ? 0.f : (y1 > IMGF ? IMGF : y1);
    x2 = x2 < 0.f ? 0.f : (x2 > IMGF ? IMGF : x2);
    y2 = y2 < 0.f ? 0.f : (y2 > IMGF ? IMGF : y2);
    float* o = b2 + ((size_t)b * NPOST + d) * 4;
    o[0] = x1; o[1] = y1; o[2] = x2; o[3] = y2;
  }
}

// ---------------- K6a: suppression bitmask, f32 exact op order; conflict-fixed mapping ----------
__global__ __launch_bounds__(256) void mask_kernel(
    const float* __restrict__ b2, unsigned long long* __restrict__ sup) {
#pragma clang fp contract(off)
  int b = blockIdx.x / 63;
  int i0 = (blockIdx.x % 63) * 16;
  __shared__ float bs[NPOST * 4];
  __shared__ float area[NPOST];
  for (int t = threadIdx.x; t < NPOST * 4; t += 256) bs[t] = b2[(size_t)b * NPOST * 4 + t];
  __syncthreads();
  for (int t = threadIdx.x; t < NPOST; t += 256)
    area[t] = (bs[t * 4 + 2] - bs[t * 4]) * (bs[t * 4 + 3] - bs[t * 4 + 1]);
  __syncthreads();
  int i = i0 + (threadIdx.x & 15);
  int wd = threadIdx.x >> 4;
  if (i >= NPOST) return;
  float ax1 = bs[i * 4], ay1 = bs[i * 4 + 1], ax2 = bs[i * 4 + 2], ay2 = bs[i * 4 + 3];
  float aa = area[i];
  unsigned long long m = 0;
  for (int bit = 0; bit < 64; ++bit) {
    int j = wd * 64 + bit;
    if (j > i && j < NPOST) {
      float lx = fmaxf(ax1, bs[j * 4]);
      float ly = fmaxf(ay1, bs[j * 4 + 1]);
      float rx = fminf(ax2, bs[j * 4 + 2]);
      float ry = fminf(ay2, bs[j * 4 + 3]);
      float iw = rx - lx; if (iw < 0.f) iw = 0.f;
      float ih = ry - ly; if (ih < 0.f) ih = 0.f;
      float inter = iw * ih;
      float denom = (aa + area[j]) - inter;
      float iou = inter / denom;
      if (iou > 0.7f) m |= 1ull << bit;
    }
  }
  sup[((size_t)b * NPOST + i) * 16 + wd] = m;
}

// ---------------- K6b: wave-synchronous NMS scan, 8-deep prefetch + compaction ----------------
__global__ __launch_bounds__(64) void nms_out(
    const unsigned long long* __restrict__ sup, const float* __restrict__ b2,
    const float* __restrict__ s2, float* __restrict__ out) {
  int b = blockIdx.x;
  int lane = threadIdx.x;
  unsigned long long kw = 0;
  if (lane < 16) kw = (lane < 15) ? ~0ull : ((1ull << 40) - 1);  // bits 960..999 valid
  const unsigned long long* ms = sup + (size_t)b * NPOST * 16;
  unsigned long long mb[8];
#pragma unroll
  for (int k = 0; k < 8; ++k)
    mb[k] = (lane < 16) ? ms[(size_t)k * 16 + lane] : 0ull;
  for (int i0 = 0; i0 < NPOST; i0 += 8) {          // 1000 = 8*125
    unsigned long long nb[8];
#pragma unroll
    for (int k = 0; k < 8; ++k) {
      int nx = i0 + 8 + k;
      nb[k] = (nx < NPOST && lane < 16) ? ms[(size_t)nx * 16 + lane] : 0ull;
    }
#pragma unroll
    for (int k = 0; k < 8; ++k) {
      int i = i0 + k;
      unsigned long long w = __shfl(kw, i >> 6, 64);  // broadcast word holding bit i
      if ((w >> (i & 63)) & 1ull) {                   // wave-uniform branch
        if (lane < 16) kw &= ~mb[k];                  // bit i never set in row i (j>i only)
      }
    }
#pragma unroll
    for (int k = 0; k < 8; ++k) mb[k] = nb[k];
  }
  __shared__ unsigned long long keeps[16];
  if (lane < 16) keeps[lane] = kw;
  __syncthreads();
  int total = 0;
#pragma unroll
  for (int k = 0; k < 16; ++k) total += __popcll(keeps[k]);
  for (int i = lane; i < NPOST; i += 64) {
    int w = i >> 6;
    int before = 0;
    for (int k = 0; k < w; ++k) before += __popcll(keeps[k]);
    before += __popcll(keeps[w] & ((1ull << (i & 63)) - 1));
    bool kept = (keeps[w] >> (i & 63)) & 1ull;
    if (kept) {
      size_t ob = (size_t)b * (NPOST * 5) + (size_t)before * 5;
      const float* src = b2 + ((size_t)b * NPOST + i) * 4;
      out[ob + 0] = src[0];
      out[ob + 1] = src[1];
      out[ob + 2] = src[2];
      out[ob + 3] = src[3];
      out[ob + 4] = s2[(size_t)b * NPOST + i];
    }
    if (i >= total) {
      size_t ob = (size_t)b * (NPOST * 5) + (size_t)i * 5;
      for (int c = 0; c < 5; ++c) out[ob + c] = 0.f;
    }
  }
}

extern "C" void kernel_launch(void* const* d_in, const int* in_sizes, int n_in,
                              void* d_out, int out_size, void* d_ws, size_t ws_size,
                              hipStream_t stream) {
  const float *x = nullptr, *conv_w = nullptr, *conv_b = nullptr,
              *box_w = nullptr, *box_b = nullptr, *obj_w = nullptr, *obj_b = nullptr;
  for (int i = 0; i < n_in; ++i) {
    switch (in_sizes[i]) {
      case 8388608: x = (const float*)d_in[i]; break;
      case 589824:  conv_w = (const float*)d_in[i]; break;
      case 256:     conv_b = (const float*)d_in[i]; break;
      case 9216:    box_w = (const float*)d_in[i]; break;
      case 36:      box_b = (const float*)d_in[i]; break;
      case 2304:    obj_w = (const float*)d_in[i]; break;
      case 9:       obj_b = (const float*)d_in[i]; break;
    }
  }
  float* out = (float*)d_out;

  char* p = (char*)d_ws;
  auto alloc = [&](size_t n) { char* q = p; p += (n + 255) & ~255ull; return (void*)q; };
  float* feats  = (float*)alloc((size_t)B_ * C_ * HW_ * 4);       // 33.55 MB
  float* tbox   = (float*)alloc((size_t)B_ * 4 * SITES * 4);      // 4.72 MB
  float* scores = (float*)alloc((size_t)B_ * SITES * 4);          // 1.18 MB
  float* xpad   = (float*)alloc((size_t)B_ * C_ * HWP_ * 4);      // 34.60 MB
  float* wq     = (float*)alloc((size_t)64 * C_ * 36 * 4);        // 2.36 MB packed 3x3 weights
  float* wt     = (float*)alloc((size_t)C_ * 45 * 4);             // 46 KB packed 1x1 weights
  float* s2     = (float*)alloc((size_t)B_ * NPOST * 4);
  float* b2     = (float*)alloc((size_t)B_ * NPOST * 4 * 4);
  unsigned long long* sup = (unsigned long long*)alloc((size_t)B_ * NPOST * 16 * 8); // 1.02 MB

  hipLaunchKernelGGL(prep, dim3(8448 + 2304 + 45), dim3(256), 0, stream,
                     x, conv_w, box_w, obj_w, xpad, wq, wt);
  hipLaunchKernelGGL(conv3_4co, dim3(B_ * 64 * 4), dim3(256), 0, stream,
                     xpad, wq, conv_b, feats);
  hipLaunchKernelGGL(conv1_all45, dim3(B_ * HW_ / 64), dim3(64), 0, stream,
                     feats, wt, box_b, obj_b, tbox, scores);
  hipLaunchKernelGGL(select_sort_decode, dim3(B_), dim3(1024), 0, stream,
                     scores, tbox, s2, b2);
  hipLaunchKernelGGL(mask_kernel, dim3(B_ * 63), dim3(256), 0, stream, b2, sup);
  hipLaunchKernelGGL(nms_out, dim3(B_), dim3(64), 0, stream, sup, b2, s2, out);
}